// Round 8
// baseline (325.828 us; speedup 1.0000x reference)
//
#include <hip/hip_runtime.h>
#include <hip/hip_bf16.h>
#include <stdint.h>

// ---------------- types ----------------
typedef __attribute__((ext_vector_type(8))) short  bf16x8;
typedef __attribute__((ext_vector_type(4))) float  f32x4;
typedef __attribute__((ext_vector_type(8))) unsigned short u16x8;

__device__ __forceinline__ unsigned short f2bf(float f) {
    union { float f; uint32_t u; } v; v.f = f;
    uint32_t u = v.u;
    uint32_t r = (u + 0x7FFFu + ((u >> 16) & 1u)) >> 16;
    return (unsigned short)r;
}
__device__ __forceinline__ float bf2f(unsigned short h) {
    union { uint32_t u; float f; } v; v.u = ((uint32_t)h) << 16;
    return v.f;
}
// HW packed f32->bf16 (RNE, bit-identical to f2bf for finite values):
// D[15:0]=bf16(a), D[31:16]=bf16(b). Replaces ~7 int-ALU ops with 1.
__device__ __forceinline__ uint32_t pk2(float a, float b) {
    uint32_t r;
    asm("v_cvt_pk_bf16_f32 %0, %1, %2" : "=v"(r) : "v"(a), "v"(b));
    return r;
}

// ---------------- constants ----------------
#define BATCH 8192
#define CIN   8
#define S0    4
#define FIN   784
#define KP1   800      // FIN padded to 25*32
#define HDIM  256
#define APITCH 40      // Path B A-tile pitch (32 + 8 pad)
#define AP2   104      // BK=64 A-tile pitch: 64 + 40 pad; 52 dwords == 20 mod 32
                       // -> identical (free, 2-way) bank pattern to APITCH=40
#define HPITCH 264     // 256 + 8 pad (shorts)

// ws layout (bytes) for fast path
#define W1T_OFF 0
#define W1T_BYTES (8u * 256u * 800u * 2u)          // 3,276,800
#define W2T_OFF (W1T_OFF + W1T_BYTES)
#define W2T_BYTES (8u * 256u * 256u * 2u)          // 1,048,576
#define YWS_OFF (W2T_OFF + W2T_BYTES)              // 4,325,376
#define WS_NEED (YWS_OFF + (size_t)BATCH * 12u * 4u)  // 4,718,592

// ============================================================
// scalar-tail math shared by both paths
// ============================================================
__device__ __forceinline__ void scalar_tail(const float* xv,  // [12]
    const float* __restrict__ inp1, const float* __restrict__ loc1,
    const float* __restrict__ inp2, const float* __restrict__ loc2,
    const float* __restrict__ inp3,
    const float* __restrict__ Wm1, const float* __restrict__ bm1,
    const float* __restrict__ Wm2, const float* __restrict__ bm2,
    float* out2)
{
    float xv1[3];
#pragma unroll
    for (int s = 0; s < 3; ++s) {
        int i1 = 0, i2 = 0; float b1v = inp1[s], b2v = -3.0e38f;
        for (int d = 1; d < 12; ++d) {
            float v = inp1[d * 3 + s];
            if (v > b1v)      { b2v = b1v; i2 = i1; b1v = v; i1 = d; }
            else if (v > b2v) { b2v = v; i2 = d; }
        }
        int m = (loc1[3 + s] > loc1[s]) ? 1 : 0;
        float v1 = xv[i1], v2 = xv[i2];
        float o = bm2[m];
#pragma unroll
        for (int j = 0; j < 12; ++j) {
            float h = v1 * Wm1[(m * 2 + 0) * 12 + j] + v2 * Wm1[(m * 2 + 1) * 12 + j] + bm1[m * 12 + j];
            h = fmaxf(h, 0.f);
            o += h * Wm2[m * 12 + j];
        }
        xv1[s] = o;
    }
    float xv2[2];
#pragma unroll
    for (int s = 0; s < 2; ++s) {
        int i1 = 0, i2 = 0; float b1v = inp2[s], b2v = -3.0e38f;
        for (int d = 1; d < 3; ++d) {
            float v = inp2[d * 2 + s];
            if (v > b1v)      { b2v = b1v; i2 = i1; b1v = v; i1 = d; }
            else if (v > b2v) { b2v = v; i2 = d; }
        }
        int m = (loc2[2 + s] > loc2[s]) ? 1 : 0;
        float v1 = xv1[i1], v2 = xv1[i2];
        float o = bm2[m];
#pragma unroll
        for (int j = 0; j < 12; ++j) {
            float h = v1 * Wm1[(m * 2 + 0) * 12 + j] + v2 * Wm1[(m * 2 + 1) * 12 + j] + bm1[m * 12 + j];
            h = fmaxf(h, 0.f);
            o += h * Wm2[m * 12 + j];
        }
        xv2[s] = o;
    }
    int j1 = (inp3[1] > inp3[0]) ? 1 : 0;
    int j2 = 1 - j1;
    out2[0] = 1.f / (1.f + expf(-xv2[j1]));
    out2[1] = 1.f / (1.f + expf(-xv2[j2]));
}

// ============================================================
// PATH A kernels
// ============================================================
// merged prep: blocks [0,1600) -> Wi1 transpose; [1600,2112) -> Wi2
__global__ void prep_weights_kernel(const float* __restrict__ Wi1, const float* __restrict__ Wi2,
                                    unsigned short* __restrict__ W1t, unsigned short* __restrict__ W2t)
{
    __shared__ float tile[32][33];
    int bx = blockIdx.x;
    const float* src; unsigned short* dst; int K, Kpad, N, ktiles, ntiles;
    if (bx < 1600) { src = Wi1; dst = W1t; K = 784; Kpad = 800; N = 256; ktiles = 25; ntiles = 8; }
    else { bx -= 1600; src = Wi2; dst = W2t; K = 256; Kpad = 256; N = 256; ktiles = 8; ntiles = 8; }

    int nt = bx % ntiles;
    int kt = (bx / ntiles) % ktiles;
    int m  = bx / (ntiles * ktiles);
    int k0 = kt * 32, n0 = nt * 32;
    int t = threadIdx.x;
    int r  = t >> 3;
    int c4 = (t & 7) * 4;

    float4 v = make_float4(0.f, 0.f, 0.f, 0.f);
    if (k0 + r < K)
        v = *(const float4*)(src + ((size_t)m * K + (k0 + r)) * N + n0 + c4);
    tile[r][c4 + 0] = v.x; tile[r][c4 + 1] = v.y;
    tile[r][c4 + 2] = v.z; tile[r][c4 + 3] = v.w;
    __syncthreads();

    int nr = r, kc = c4;
    ushort4 ov;
    ov.x = f2bf(tile[kc + 0][nr]);
    ov.y = f2bf(tile[kc + 1][nr]);
    ov.z = f2bf(tile[kc + 2][nr]);
    ov.w = f2bf(tile[kc + 3][nr]);
    *(ushort4*)(dst + ((size_t)m * N + n0 + nr) * Kpad + k0 + kc) = ov;
}

// main fused img-level kernel v6 = v5 (BK=64, 13 barriers, slot-major XCD map)
// + v_cvt_pk_bf16_f32 staging pack: 16 scalar f2bf (~56 VALU ops) -> 8 cvt_pk
// per thread per interval. Bit-identical rounding (both RNE); pure VALU cut
// on the per-interval critical path that co-issues against 32 MFMAs.
__global__ __launch_bounds__(256, 1) void img_gemm_kernel(
    const float* __restrict__ x,
    const float* __restrict__ inp0, const float* __restrict__ loc0,
    const unsigned short* __restrict__ W1t, const unsigned short* __restrict__ W2t,
    const float* __restrict__ bi1, const float* __restrict__ bi2,
    const float* __restrict__ Wi3, const float* __restrict__ bi3,
    float* __restrict__ yws)
{
    __shared__ __align__(16) unsigned short Abuf[2][64 * AP2];
    __shared__ __align__(16) unsigned short Hbuf[64 * HPITCH];
    __shared__ float bias1s[256];
    __shared__ float bias2s[256];
    __shared__ float W3s[768];
    __shared__ float b3s[3];

    const int t  = threadIdx.x;
    const int bx = blockIdx.x;
    const int s  = (bx & 7) >> 1;                 // XCD pair -> one slot
    const int rt = ((bx >> 3) << 1) | (bx & 1);   // 0..127
    const int b0 = rt * 64;

    // routing (straight-through forward == hard argmax)
    int cs = 0; { float bv = inp0[s];
        for (int c = 1; c < CIN; ++c) { float v = inp0[c * S0 + s]; if (v > bv) { bv = v; cs = c; } } }
    int ms = 0; { float bv = loc0[s];
        for (int m = 1; m < 8; ++m) { float v = loc0[m * S0 + s]; if (v > bv) { bv = v; ms = m; } } }

    // stage biases / W3 (covered by the prologue barrier)
    bias1s[t] = bi1[ms * 256 + t];
    bias2s[t] = bi2[ms * 256 + t];
    W3s[t * 3 + 0] = Wi3[((size_t)ms * 256 + t) * 3 + 0];
    W3s[t * 3 + 1] = Wi3[((size_t)ms * 256 + t) * 3 + 1];
    W3s[t * 3 + 2] = Wi3[((size_t)ms * 256 + t) * 3 + 2];
    if (t < 3) b3s[t] = bi3[ms * 3 + t];

    const int w    = t >> 6;
    const int l    = t & 63;
    const int quad = l >> 4;
    const int lr   = l & 15;

    f32x4 acc[4][4];
#pragma unroll
    for (int i = 0; i < 4; ++i)
#pragma unroll
        for (int j = 0; j < 4; ++j) acc[i][j] = (f32x4){0.f, 0.f, 0.f, 0.f};

    // A staging coords: 64 rows x 64 k per BK-iter; per thread 16 floats
    const int ar = t >> 2;          // 0..63 (A row)
    const int ak = (t & 3) * 8;     // 0,8,16,24
    const float* xrow = x + ((size_t)(b0 + ar) * CIN + cs) * FIN;
    const int ldsw = ar * AP2 + ak;

    const unsigned short* b1base = W1t + ((size_t)ms * 256 + w * 64 + lr) * KP1 + quad * 8;

    union U8 { bf16x8 v; uint32_t u[4]; };

    // =================== layer 1: K = 800 = 12*64 + 32 ===================
    float4 xf0, xf1, xf2, xf3;
    // load + stage BK0 (k 0..63, all in-bounds)
    xf0 = *(const float4*)(xrow + ak);
    xf1 = *(const float4*)(xrow + ak + 4);
    xf2 = *(const float4*)(xrow + ak + 32);
    xf3 = *(const float4*)(xrow + ak + 36);
    {
        U8 p0, p1;
        p0.u[0] = pk2(xf0.x, xf0.y); p0.u[1] = pk2(xf0.z, xf0.w);
        p0.u[2] = pk2(xf1.x, xf1.y); p0.u[3] = pk2(xf1.z, xf1.w);
        p1.u[0] = pk2(xf2.x, xf2.y); p1.u[1] = pk2(xf2.z, xf2.w);
        p1.u[2] = pk2(xf3.x, xf3.y); p1.u[3] = pk2(xf3.z, xf3.w);
        *(bf16x8*)&Abuf[0][ldsw]      = p0.v;
        *(bf16x8*)&Abuf[0][ldsw + 32] = p1.v;
    }
    // prefetch BK1 (k 64..127, in-bounds)
    xf0 = *(const float4*)(xrow + 64 + ak);
    xf1 = *(const float4*)(xrow + 64 + ak + 4);
    xf2 = *(const float4*)(xrow + 64 + ak + 32);
    xf3 = *(const float4*)(xrow + 64 + ak + 36);
    // B chunks 0,1
    bf16x8 bcur[8], bnxt[8];
#pragma unroll
    for (int nt = 0; nt < 4; ++nt) {
        bcur[nt]     = *(const bf16x8*)(b1base + nt * 16 * KP1);
        bcur[nt + 4] = *(const bf16x8*)(b1base + nt * 16 * KP1 + 32);
    }
    __syncthreads();

#pragma unroll 1
    for (int j = 0; j < 12; ++j) {
        // (1) B prefetch for next BK-iter (L2-hot panel)
        {
            const int c0 = (j < 11) ? (2 * j + 2) * 32 : 768;   // j==11: tail chunk 24
            const int c1 = (j < 11) ? (2 * j + 3) * 32 : 0;     // j==11: dummy
#pragma unroll
            for (int nt = 0; nt < 4; ++nt) {
                bnxt[nt]     = *(const bf16x8*)(b1base + nt * 16 * KP1 + c0);
                bnxt[nt + 4] = *(const bf16x8*)(b1base + nt * 16 * KP1 + c1);
            }
        }
        // (2) stage BK j+1 from regs (cvt_pk: 8 ops, was ~56)
        {
            unsigned short* abn = Abuf[(j + 1) & 1];
            U8 p0, p1;
            p0.u[0] = pk2(xf0.x, xf0.y); p0.u[1] = pk2(xf0.z, xf0.w);
            p0.u[2] = pk2(xf1.x, xf1.y); p0.u[3] = pk2(xf1.z, xf1.w);
            p1.u[0] = pk2(xf2.x, xf2.y); p1.u[1] = pk2(xf2.z, xf2.w);
            p1.u[2] = pk2(xf3.x, xf3.y); p1.u[3] = pk2(xf3.z, xf3.w);
            *(bf16x8*)&abn[ldsw]      = p0.v;
            *(bf16x8*)&abn[ldsw + 32] = p1.v;
        }
        // (3) x prefetch for BK j+2
        if (j < 10) {
            const int base = (j + 2) * 64;
            xf0 = *(const float4*)(xrow + base + ak);
            xf1 = *(const float4*)(xrow + base + ak + 4);
            xf2 = *(const float4*)(xrow + base + ak + 32);
            xf3 = *(const float4*)(xrow + base + ak + 36);
        } else if (j == 10) {
            // BK12 tail: k 768..799 (valid < 784), 800..831 all OOB
            const int g0 = 768 + ak;
            xf0 = (g0     < FIN) ? *(const float4*)(xrow + g0)     : make_float4(0.f,0.f,0.f,0.f);
            xf1 = (g0 + 4 < FIN) ? *(const float4*)(xrow + g0 + 4) : make_float4(0.f,0.f,0.f,0.f);
            xf2 = make_float4(0.f,0.f,0.f,0.f);
            xf3 = make_float4(0.f,0.f,0.f,0.f);
        }
        // (4) compute BK j: 2 sub-chunks x 16 MFMA
        {
            const unsigned short* ab = Abuf[j & 1];
            bf16x8 afr[4];
#pragma unroll
            for (int mt = 0; mt < 4; ++mt)
                afr[mt] = *(const bf16x8*)&ab[(mt * 16 + lr) * AP2 + quad * 8];
#pragma unroll
            for (int mt = 0; mt < 4; ++mt)
#pragma unroll
                for (int nt = 0; nt < 4; ++nt)
                    acc[mt][nt] = __builtin_amdgcn_mfma_f32_16x16x32_bf16(afr[mt], bcur[nt], acc[mt][nt], 0, 0, 0);
#pragma unroll
            for (int mt = 0; mt < 4; ++mt)
                afr[mt] = *(const bf16x8*)&ab[(mt * 16 + lr) * AP2 + 32 + quad * 8];
#pragma unroll
            for (int mt = 0; mt < 4; ++mt)
#pragma unroll
                for (int nt = 0; nt < 4; ++nt)
                    acc[mt][nt] = __builtin_amdgcn_mfma_f32_16x16x32_bf16(afr[mt], bcur[nt + 4], acc[mt][nt], 0, 0, 0);
        }
#pragma unroll
        for (int q = 0; q < 8; ++q) bcur[q] = bnxt[q];
        __syncthreads();
    }
    // tail: BK12 (chunk 24) from Abuf[0], B in bcur[0..3]
    {
        bf16x8 afr[4];
#pragma unroll
        for (int mt = 0; mt < 4; ++mt)
            afr[mt] = *(const bf16x8*)&Abuf[0][(mt * 16 + lr) * AP2 + quad * 8];
#pragma unroll
        for (int mt = 0; mt < 4; ++mt)
#pragma unroll
            for (int nt = 0; nt < 4; ++nt)
                acc[mt][nt] = __builtin_amdgcn_mfma_f32_16x16x32_bf16(afr[mt], bcur[nt], acc[mt][nt], 0, 0, 0);
    }

    // prefetch first B2 chunk (latency hides under VALU epilogue)
    const unsigned short* b2base = W2t + ((size_t)ms * 256 + w * 64 + lr) * 256 + quad * 8;
#pragma unroll
    for (int nt = 0; nt < 4; ++nt)
        bcur[nt] = *(const bf16x8*)(b2base + nt * 16 * 256);

    // epilogue 1: bias + relu -> Hbuf (bf16), reset acc
#pragma unroll
    for (int mt = 0; mt < 4; ++mt)
#pragma unroll
        for (int nt = 0; nt < 4; ++nt) {
            int col = w * 64 + nt * 16 + lr;
            float bb = bias1s[col];
#pragma unroll
            for (int r = 0; r < 4; ++r) {
                int row = mt * 16 + quad * 4 + r;
                float v = acc[mt][nt][r] + bb;
                v = fmaxf(v, 0.f);
                Hbuf[row * HPITCH + col] = f2bf(v);
                acc[mt][nt][r] = 0.f;
            }
        }
    __syncthreads();

    // =================== layer 2: K = 256 (8 chunks) — barrier-free ===================
#pragma unroll
    for (int kc = 0; kc < 8; ++kc) {
        const int k0 = kc * 32;
        {
            const int koff_n = (kc < 7) ? (kc + 1) * 32 : 0;
#pragma unroll
            for (int nt = 0; nt < 4; ++nt)
                bnxt[nt] = *(const bf16x8*)(b2base + nt * 16 * 256 + koff_n);
        }
        bf16x8 afr[4];
#pragma unroll
        for (int mt = 0; mt < 4; ++mt)
            afr[mt] = *(const bf16x8*)&Hbuf[(mt * 16 + lr) * HPITCH + k0 + quad * 8];
#pragma unroll
        for (int mt = 0; mt < 4; ++mt)
#pragma unroll
            for (int nt = 0; nt < 4; ++nt)
                acc[mt][nt] = __builtin_amdgcn_mfma_f32_16x16x32_bf16(afr[mt], bcur[nt], acc[mt][nt], 0, 0, 0);
#pragma unroll
        for (int nt = 0; nt < 4; ++nt) bcur[nt] = bnxt[nt];
    }
    __syncthreads();   // all Hbuf reads done before overwrite

    // epilogue 2: bias + relu -> Hbuf (h2)
#pragma unroll
    for (int mt = 0; mt < 4; ++mt)
#pragma unroll
        for (int nt = 0; nt < 4; ++nt) {
            int col = w * 64 + nt * 16 + lr;
            float bb = bias2s[col];
#pragma unroll
            for (int r = 0; r < 4; ++r) {
                int row = mt * 16 + quad * 4 + r;
                float v = acc[mt][nt][r] + bb;
                v = fmaxf(v, 0.f);
                Hbuf[row * HPITCH + col] = f2bf(v);
            }
        }
    __syncthreads();

    // layer 3: h2[64x256] @ W3[256x3]
    if (t < 192) {
        int row = t & 63;
        int o   = t >> 6;
        float a3 = b3s[o];
        for (int j = 0; j < 256; j += 8) {
            u16x8 hv = *(const u16x8*)&Hbuf[row * HPITCH + j];
#pragma unroll
            for (int jj = 0; jj < 8; ++jj)
                a3 += bf2f(hv[jj]) * W3s[(j + jj) * 3 + o];
        }
        yws[(size_t)(b0 + row) * 12 + s * 3 + o] = a3;
    }
}

__global__ void tail_kernel(const float* __restrict__ yws,
                            const float* __restrict__ inp1, const float* __restrict__ loc1,
                            const float* __restrict__ inp2, const float* __restrict__ loc2,
                            const float* __restrict__ inp3,
                            const float* __restrict__ Wm1, const float* __restrict__ bm1,
                            const float* __restrict__ Wm2, const float* __restrict__ bm2,
                            float* __restrict__ out)
{
    int b = blockIdx.x * 256 + threadIdx.x;
    float xv[12];
    const float* p = yws + (size_t)b * 12;
#pragma unroll
    for (int i = 0; i < 12; ++i) xv[i] = p[i];
    float o2[2];
    scalar_tail(xv, inp1, loc1, inp2, loc2, inp3, Wm1, bm1, Wm2, bm2, o2);
    out[(size_t)b * 2 + 0] = o2[0];
    out[(size_t)b * 2 + 1] = o2[1];
}

// ============================================================
// PATH B: zero-workspace fully-fused fallback (unchanged)
// ============================================================
#define BPITCH 40
__global__ __launch_bounds__(256, 1) void fused_all_kernel(
    const float* __restrict__ x,
    const float* __restrict__ inp0, const float* __restrict__ loc0,
    const float* __restrict__ Wi1, const float* __restrict__ bi1,
    const float* __restrict__ Wi2, const float* __restrict__ bi2,
    const float* __restrict__ Wi3, const float* __restrict__ bi3,
    const float* __restrict__ inp1, const float* __restrict__ loc1,
    const float* __restrict__ inp2, const float* __restrict__ loc2,
    const float* __restrict__ inp3,
    const float* __restrict__ Wm1, const float* __restrict__ bm1,
    const float* __restrict__ Wm2, const float* __restrict__ bm2,
    float* __restrict__ out)
{
    __shared__ __align__(16) unsigned short Abuf[64 * APITCH];
    __shared__ __align__(16) unsigned short Bbuf[256 * BPITCH];
    __shared__ __align__(16) unsigned short Hbuf[64 * HPITCH];
    __shared__ float bias1s[256];
    __shared__ float bias2s[256];
    __shared__ float W3s[768];
    __shared__ float b3s[3];

    const int t  = threadIdx.x;
    const int b0 = blockIdx.x * 64;
    const int w    = t >> 6;
    const int l    = t & 63;
    const int quad = l >> 4;
    const int lr   = l & 15;
    const int ar = t >> 2;
    const int ak = (t & 3) * 8;
    const int wk  = t & 31;
    const int wn0 = (t >> 5) * 32;

    float yreg[4];

#pragma unroll 1
    for (int s = 0; s < 4; ++s) {
        int cs = 0; { float bv = inp0[s];
            for (int c = 1; c < CIN; ++c) { float v = inp0[c * S0 + s]; if (v > bv) { bv = v; cs = c; } } }
        int ms = 0; { float bv = loc0[s];
            for (int m = 1; m < 8; ++m) { float v = loc0[m * S0 + s]; if (v > bv) { bv = v; ms = m; } } }

        __syncthreads();
        bias1s[t] = bi1[ms * 256 + t];
        bias2s[t] = bi2[ms * 256 + t];
        W3s[t * 3 + 0] = Wi3[((size_t)ms * 256 + t) * 3 + 0];
        W3s[t * 3 + 1] = Wi3[((size_t)ms * 256 + t) * 3 + 1];
        W3s[t * 3 + 2] = Wi3[((size_t)ms * 256 + t) * 3 + 2];
        if (t < 3) b3s[t] = bi3[ms * 3 + t];

        f32x4 acc[4][4];
#pragma unroll
        for (int i = 0; i < 4; ++i)
#pragma unroll
            for (int j = 0; j < 4; ++j) acc[i][j] = (f32x4){0.f, 0.f, 0.f, 0.f};

        const float* xbase = x + ((size_t)b0 * CIN + cs) * FIN;
        const float* w1m   = Wi1 + (size_t)ms * FIN * 256;

        for (int kc = 0; kc < 25; ++kc) {
            const int k0 = kc * 32;
            {
                int gk = k0 + ak;
                bf16x8 av;
                if (gk < FIN) {
                    const float* p = xbase + (size_t)ar * (CIN * FIN) + gk;
                    float4 f0 = *(const float4*)(p);
                    float4 f1 = *(const float4*)(p + 4);
                    av[0] = (short)f2bf(f0.x); av[1] = (short)f2bf(f0.y);
                    av[2] = (short)f2bf(f0.z); av[3] = (short)f2bf(f0.w);
                    av[4] = (short)f2bf(f1.x); av[5] = (short)f2bf(f1.y);
                    av[6] = (short)f2bf(f1.z); av[7] = (short)f2bf(f1.w);
                } else {
                    av = (bf16x8){0,0,0,0,0,0,0,0};
                }
                *(bf16x8*)&Abuf[ar * APITCH + ak] = av;
            }
            {
                int gk = k0 + wk;
                if (gk < FIN) {
                    const float* wp = w1m + (size_t)gk * 256 + wn0;
#pragma unroll
                    for (int i = 0; i < 32; i += 4) {
                        float4 f = *(const float4*)(wp + i);
                        Bbuf[(wn0 + i + 0) * BPITCH + wk] = f2bf(f.x);
                        Bbuf[(wn0 + i + 1) * BPITCH + wk] = f2bf(f.y);
                        Bbuf[(wn0 + i + 2) * BPITCH + wk] = f2bf(f.z);
                        Bbuf[(wn0 + i + 3) * BPITCH + wk] = f2bf(f.w);
                    }
                } else {
#pragma unroll
                    for (int i = 0; i < 32; ++i)
                        Bbuf[(wn0 + i) * BPITCH + wk] = 0;
                }
            }
            __syncthreads();

            bf16x8 afr[4], bfr[4];
#pragma unroll
            for (int mt = 0; mt < 4; ++mt)
                afr[mt] = *(const bf16x8*)&Abuf[(mt * 16 + lr) * APITCH + quad * 8];
#pragma unroll
            for (int nt = 0; nt < 4; ++nt)
                bfr[nt] = *(const bf16x8*)&Bbuf[(w * 64 + nt * 16 + lr) * BPITCH + quad * 8];
#pragma unroll
            for (int mt = 0; mt < 4; ++mt)
#pragma unroll
                for (int nt = 0; nt < 4; ++nt)
                    acc[mt][nt] = __builtin_amdgcn_mfma_f32_16x16x32_bf16(afr[mt], bfr[nt], acc[mt][nt], 0, 0, 0);
            __syncthreads();
        }

#pragma unroll
        for (int mt = 0; mt < 4; ++mt)
#pragma unroll
            for (int nt = 0; nt < 4; ++nt) {
                int col = w * 64 + nt * 16 + lr;
                float bb = bias1s[col];
#pragma unroll
                for (int r = 0; r < 4; ++r) {
                    int row = mt * 16 + quad * 4 + r;
                    float v = acc[mt][nt][r] + bb;
                    v = fmaxf(v, 0.f);
                    Hbuf[row * HPITCH + col] = f2bf(v);
                    acc[mt][nt][r] = 0.f;
                }
            }
        __syncthreads();

        const float* w2m = Wi2 + (size_t)ms * 256 * 256;
        for (int kc = 0; kc < 8; ++kc) {
            const int k0 = kc * 32;
            {
                const float* wp = w2m + (size_t)(k0 + wk) * 256 + wn0;
#pragma unroll
                for (int i = 0; i < 32; i += 4) {
                    float4 f = *(const float4*)(wp + i);
                    Bbuf[(wn0 + i + 0) * BPITCH + wk] = f2bf(f.x);
                    Bbuf[(wn0 + i + 1) * BPITCH + wk] = f2bf(f.y);
                    Bbuf[(wn0 + i + 2) * BPITCH + wk] = f2bf(f.z);
                    Bbuf[(wn0 + i + 3) * BPITCH + wk] = f2bf(f.w);
                }
            }
            __syncthreads();

            bf16x8 afr[4], bfr[4];
#pragma unroll
            for (int mt = 0; mt < 4; ++mt)
                afr[mt] = *(const bf16x8*)&Hbuf[(mt * 16 + lr) * HPITCH + k0 + quad * 8];
#pragma unroll
            for (int nt = 0; nt < 4; ++nt)
                bfr[nt] = *(const bf16x8*)&Bbuf[(w * 64 + nt * 16 + lr) * BPITCH + quad * 8];
#pragma unroll
            for (int mt = 0; mt < 4; ++mt)
#pragma unroll
                for (int nt = 0; nt < 4; ++nt)
                    acc[mt][nt] = __builtin_amdgcn_mfma_f32_16x16x32_bf16(afr[mt], bfr[nt], acc[mt][nt], 0, 0, 0);
            __syncthreads();
        }

#pragma unroll
        for (int mt = 0; mt < 4; ++mt)
#pragma unroll
            for (int nt = 0; nt < 4; ++nt) {
                int col = w * 64 + nt * 16 + lr;
                float bb = bias2s[col];
#pragma unroll
                for (int r = 0; r < 4; ++r) {
                    int row = mt * 16 + quad * 4 + r;
                    float v = acc[mt][nt][r] + bb;
                    v = fmaxf(v, 0.f);
                    Hbuf[row * HPITCH + col] = f2bf(v);
                }
            }
        __syncthreads();

        if (t < 192) {
            int row = t & 63;
            int o   = t >> 6;
            float a3 = b3s[o];
            for (int j = 0; j < 256; j += 8) {
                u16x8 hv = *(const u16x8*)&Hbuf[row * HPITCH + j];
#pragma unroll
                for (int jj = 0; jj < 8; ++jj)
                    a3 += bf2f(hv[jj]) * W3s[(j + jj) * 3 + o];
            }
            yreg[s] = a3;
        }
    }

    __syncthreads();
    float* ybuf = (float*)Abuf;
    if (t < 192) {
        int row = t & 63;
        int o   = t >> 6;
#pragma unroll
        for (int s = 0; s < 4; ++s)
            ybuf[row * 12 + s * 3 + o] = yreg[s];
    }
    __syncthreads();
    if (t < 64) {
        float xv[12];
#pragma unroll
        for (int i = 0; i < 12; ++i) xv[i] = ybuf[t * 12 + i];
        float o2[2];
        scalar_tail(xv, inp1, loc1, inp2, loc2, inp3, Wm1, bm1, Wm2, bm2, o2);
        out[(size_t)(b0 + t) * 2 + 0] = o2[0];
        out[(size_t)(b0 + t) * 2 + 1] = o2[1];
    }
}

// ---------------- launcher ----------------
extern "C" void kernel_launch(void* const* d_in, const int* in_sizes, int n_in,
                              void* d_out, int out_size, void* d_ws, size_t ws_size,
                              hipStream_t stream) {
    if (n_in < 18) return;
    const float* x    = (const float*)d_in[0];
    const float* inp0 = (const float*)d_in[1];
    const float* loc0 = (const float*)d_in[2];
    const float* inp1 = (const float*)d_in[3];
    const float* loc1 = (const float*)d_in[4];
    const float* inp2 = (const float*)d_in[5];
    const float* loc2 = (const float*)d_in[6];
    const float* inp3 = (const float*)d_in[7];
    const float* Wi1  = (const float*)d_in[8];
    const float* bi1  = (const float*)d_in[9];
    const float* Wi2  = (const float*)d_in[10];
    const float* bi2  = (const float*)d_in[11];
    const float* Wi3  = (const float*)d_in[12];
    const float* bi3  = (const float*)d_in[13];
    const float* Wm1  = (const float*)d_in[14];
    const float* bm1  = (const float*)d_in[15];
    const float* Wm2  = (const float*)d_in[16];
    const float* bm2  = (const float*)d_in[17];
    float* out = (float*)d_out;

    if (ws_size >= WS_NEED && d_ws != nullptr) {
        unsigned short* W1t = (unsigned short*)((char*)d_ws + W1T_OFF);
        unsigned short* W2t = (unsigned short*)((char*)d_ws + W2T_OFF);
        float*          yws = (float*)((char*)d_ws + YWS_OFF);

        prep_weights_kernel<<<2112, 256, 0, stream>>>(Wi1, Wi2, W1t, W2t);
        img_gemm_kernel<<<512, 256, 0, stream>>>(x, inp0, loc0, W1t, W2t, bi1, bi2, Wi3, bi3, yws);
        tail_kernel<<<BATCH / 256, 256, 0, stream>>>(yws, inp1, loc1, inp2, loc2, inp3,
                                                     Wm1, bm1, Wm2, bm2, out);
    } else {
        fused_all_kernel<<<BATCH / 64, 256, 0, stream>>>(
            x, inp0, loc0, Wi1, bi1, Wi2, bi2, Wi3, bi3,
            inp1, loc1, inp2, loc2, inp3, Wm1, bm1, Wm2, bm2, out);
    }
}

// Round 9
// 323.246 us; speedup vs baseline: 1.0080x; 1.0080x over previous
//
#include <hip/hip_runtime.h>
#include <hip/hip_bf16.h>
#include <stdint.h>

// ---------------- types ----------------
typedef __attribute__((ext_vector_type(8))) short  bf16x8;
typedef __attribute__((ext_vector_type(4))) float  f32x4;
typedef __attribute__((ext_vector_type(8))) unsigned short u16x8;

__device__ __forceinline__ unsigned short f2bf(float f) {
    union { float f; uint32_t u; } v; v.f = f;
    uint32_t u = v.u;
    uint32_t r = (u + 0x7FFFu + ((u >> 16) & 1u)) >> 16;
    return (unsigned short)r;
}
__device__ __forceinline__ float bf2f(unsigned short h) {
    union { uint32_t u; float f; } v; v.u = ((uint32_t)h) << 16;
    return v.f;
}

// ---------------- constants ----------------
#define BATCH 8192
#define CIN   8
#define S0    4
#define FIN   784
#define KP1   800      // FIN padded to 25*32
#define HDIM  256
#define APITCH 40      // Path B A-tile pitch (32 + 8 pad)
#define AP2   104      // BK=64 A-tile pitch: 64 + 40 pad; 52 dwords == 20 mod 32
                       // -> identical (free, 2-way) bank pattern to APITCH=40
#define HPITCH 264     // 256 + 8 pad (shorts)

// ws layout (bytes) for fast path
#define W1T_OFF 0
#define W1T_BYTES (8u * 256u * 800u * 2u)          // 3,276,800
#define W2T_OFF (W1T_OFF + W1T_BYTES)
#define W2T_BYTES (8u * 256u * 256u * 2u)          // 1,048,576
#define YWS_OFF (W2T_OFF + W2T_BYTES)              // 4,325,376
#define WS_NEED (YWS_OFF + (size_t)BATCH * 12u * 4u)  // 4,718,592

// ============================================================
// scalar-tail math shared by both paths
// ============================================================
__device__ __forceinline__ void scalar_tail(const float* xv,  // [12]
    const float* __restrict__ inp1, const float* __restrict__ loc1,
    const float* __restrict__ inp2, const float* __restrict__ loc2,
    const float* __restrict__ inp3,
    const float* __restrict__ Wm1, const float* __restrict__ bm1,
    const float* __restrict__ Wm2, const float* __restrict__ bm2,
    float* out2)
{
    float xv1[3];
#pragma unroll
    for (int s = 0; s < 3; ++s) {
        int i1 = 0, i2 = 0; float b1v = inp1[s], b2v = -3.0e38f;
        for (int d = 1; d < 12; ++d) {
            float v = inp1[d * 3 + s];
            if (v > b1v)      { b2v = b1v; i2 = i1; b1v = v; i1 = d; }
            else if (v > b2v) { b2v = v; i2 = d; }
        }
        int m = (loc1[3 + s] > loc1[s]) ? 1 : 0;
        float v1 = xv[i1], v2 = xv[i2];
        float o = bm2[m];
#pragma unroll
        for (int j = 0; j < 12; ++j) {
            float h = v1 * Wm1[(m * 2 + 0) * 12 + j] + v2 * Wm1[(m * 2 + 1) * 12 + j] + bm1[m * 12 + j];
            h = fmaxf(h, 0.f);
            o += h * Wm2[m * 12 + j];
        }
        xv1[s] = o;
    }
    float xv2[2];
#pragma unroll
    for (int s = 0; s < 2; ++s) {
        int i1 = 0, i2 = 0; float b1v = inp2[s], b2v = -3.0e38f;
        for (int d = 1; d < 3; ++d) {
            float v = inp2[d * 2 + s];
            if (v > b1v)      { b2v = b1v; i2 = i1; b1v = v; i1 = d; }
            else if (v > b2v) { b2v = v; i2 = d; }
        }
        int m = (loc2[2 + s] > loc2[s]) ? 1 : 0;
        float v1 = xv1[i1], v2 = xv1[i2];
        float o = bm2[m];
#pragma unroll
        for (int j = 0; j < 12; ++j) {
            float h = v1 * Wm1[(m * 2 + 0) * 12 + j] + v2 * Wm1[(m * 2 + 1) * 12 + j] + bm1[m * 12 + j];
            h = fmaxf(h, 0.f);
            o += h * Wm2[m * 12 + j];
        }
        xv2[s] = o;
    }
    int j1 = (inp3[1] > inp3[0]) ? 1 : 0;
    int j2 = 1 - j1;
    out2[0] = 1.f / (1.f + expf(-xv2[j1]));
    out2[1] = 1.f / (1.f + expf(-xv2[j2]));
}

// ============================================================
// PATH A kernels
// ============================================================
// merged prep: blocks [0,1600) -> Wi1 transpose; [1600,2112) -> Wi2
__global__ void prep_weights_kernel(const float* __restrict__ Wi1, const float* __restrict__ Wi2,
                                    unsigned short* __restrict__ W1t, unsigned short* __restrict__ W2t)
{
    __shared__ float tile[32][33];
    int bx = blockIdx.x;
    const float* src; unsigned short* dst; int K, Kpad, N, ktiles, ntiles;
    if (bx < 1600) { src = Wi1; dst = W1t; K = 784; Kpad = 800; N = 256; ktiles = 25; ntiles = 8; }
    else { bx -= 1600; src = Wi2; dst = W2t; K = 256; Kpad = 256; N = 256; ktiles = 8; ntiles = 8; }

    int nt = bx % ntiles;
    int kt = (bx / ntiles) % ktiles;
    int m  = bx / (ntiles * ktiles);
    int k0 = kt * 32, n0 = nt * 32;
    int t = threadIdx.x;
    int r  = t >> 3;
    int c4 = (t & 7) * 4;

    float4 v = make_float4(0.f, 0.f, 0.f, 0.f);
    if (k0 + r < K)
        v = *(const float4*)(src + ((size_t)m * K + (k0 + r)) * N + n0 + c4);
    tile[r][c4 + 0] = v.x; tile[r][c4 + 1] = v.y;
    tile[r][c4 + 2] = v.z; tile[r][c4 + 3] = v.w;
    __syncthreads();

    int nr = r, kc = c4;
    ushort4 ov;
    ov.x = f2bf(tile[kc + 0][nr]);
    ov.y = f2bf(tile[kc + 1][nr]);
    ov.z = f2bf(tile[kc + 2][nr]);
    ov.w = f2bf(tile[kc + 3][nr]);
    *(ushort4*)(dst + ((size_t)m * N + n0 + nr) * Kpad + k0 + kc) = ov;
}

// main fused img-level kernel v7 = v5 (BK=64, 13 barriers, slot-major XCD map)
// + DEPTH-2 x prefetch: even intervals stage from reg-set A then reload A with
// BK j+3; odd intervals use set B. Each x-load now has a 2-interval tolerance
// (~1000+ cy >= HBM ~900 cy latency, m126) so the s_waitcnt before the
// ds_write stops exposing HBM latency. Zero register copies; +16 VGPR.
__global__ __launch_bounds__(256, 1) void img_gemm_kernel(
    const float* __restrict__ x,
    const float* __restrict__ inp0, const float* __restrict__ loc0,
    const unsigned short* __restrict__ W1t, const unsigned short* __restrict__ W2t,
    const float* __restrict__ bi1, const float* __restrict__ bi2,
    const float* __restrict__ Wi3, const float* __restrict__ bi3,
    float* __restrict__ yws)
{
    __shared__ __align__(16) unsigned short Abuf[2][64 * AP2];
    __shared__ __align__(16) unsigned short Hbuf[64 * HPITCH];
    __shared__ float bias1s[256];
    __shared__ float bias2s[256];
    __shared__ float W3s[768];
    __shared__ float b3s[3];

    const int t  = threadIdx.x;
    const int bx = blockIdx.x;
    const int s  = (bx & 7) >> 1;                 // XCD pair -> one slot
    const int rt = ((bx >> 3) << 1) | (bx & 1);   // 0..127
    const int b0 = rt * 64;

    // routing (straight-through forward == hard argmax)
    int cs = 0; { float bv = inp0[s];
        for (int c = 1; c < CIN; ++c) { float v = inp0[c * S0 + s]; if (v > bv) { bv = v; cs = c; } } }
    int ms = 0; { float bv = loc0[s];
        for (int m = 1; m < 8; ++m) { float v = loc0[m * S0 + s]; if (v > bv) { bv = v; ms = m; } } }

    // stage biases / W3 (covered by the prologue barrier)
    bias1s[t] = bi1[ms * 256 + t];
    bias2s[t] = bi2[ms * 256 + t];
    W3s[t * 3 + 0] = Wi3[((size_t)ms * 256 + t) * 3 + 0];
    W3s[t * 3 + 1] = Wi3[((size_t)ms * 256 + t) * 3 + 1];
    W3s[t * 3 + 2] = Wi3[((size_t)ms * 256 + t) * 3 + 2];
    if (t < 3) b3s[t] = bi3[ms * 3 + t];

    const int w    = t >> 6;
    const int l    = t & 63;
    const int quad = l >> 4;
    const int lr   = l & 15;

    f32x4 acc[4][4];
#pragma unroll
    for (int i = 0; i < 4; ++i)
#pragma unroll
        for (int j = 0; j < 4; ++j) acc[i][j] = (f32x4){0.f, 0.f, 0.f, 0.f};

    // A staging coords: 64 rows x 64 k per BK-iter; per thread 16 floats
    const int ar = t >> 2;          // 0..63 (A row)
    const int ak = (t & 3) * 8;     // 0,8,16,24
    const float* xrow = x + ((size_t)(b0 + ar) * CIN + cs) * FIN;
    const int ldsw = ar * AP2 + ak;

    const unsigned short* b1base = W1t + ((size_t)ms * 256 + w * 64 + lr) * KP1 + quad * 8;

    bf16x8 bcur[8], bnxt[8];

    // one L1 interval: B prefetch -> stage BK j+1 from X regs -> optional x
    // reload of BK j+3 into the SAME X regs -> 32 MFMA on BK j -> barrier.
    auto l1_interval = [&](int j, float4& X0, float4& X1, float4& X2, float4& X3,
                           bool do_load, bool do_tail) {
        // (1) B prefetch for next BK-iter (L2-hot panel)
        const int c0 = (j < 11) ? (2 * j + 2) * 32 : 768;   // j==11: tail chunk 24
        const int c1 = (j < 11) ? (2 * j + 3) * 32 : 0;     // j==11: dummy
#pragma unroll
        for (int nt = 0; nt < 4; ++nt) {
            bnxt[nt]     = *(const bf16x8*)(b1base + nt * 16 * KP1 + c0);
            bnxt[nt + 4] = *(const bf16x8*)(b1base + nt * 16 * KP1 + c1);
        }
        // (2) stage BK j+1 from X regs (loaded 2 intervals ago)
        {
            unsigned short* abn = Abuf[(j + 1) & 1];
            bf16x8 v0, v1;
            v0[0]=(short)f2bf(X0.x); v0[1]=(short)f2bf(X0.y); v0[2]=(short)f2bf(X0.z); v0[3]=(short)f2bf(X0.w);
            v0[4]=(short)f2bf(X1.x); v0[5]=(short)f2bf(X1.y); v0[6]=(short)f2bf(X1.z); v0[7]=(short)f2bf(X1.w);
            v1[0]=(short)f2bf(X2.x); v1[1]=(short)f2bf(X2.y); v1[2]=(short)f2bf(X2.z); v1[3]=(short)f2bf(X2.w);
            v1[4]=(short)f2bf(X3.x); v1[5]=(short)f2bf(X3.y); v1[6]=(short)f2bf(X3.z); v1[7]=(short)f2bf(X3.w);
            *(bf16x8*)&abn[ldsw]      = v0;
            *(bf16x8*)&abn[ldsw + 32] = v1;
        }
        // (3) reload X regs with BK j+3 (consumed at interval j+2)
        if (do_load) {
            const int base = (j + 3) * 64;   // j+3 <= 11 -> all k < 768+64, in-bounds
            X0 = *(const float4*)(xrow + base + ak);
            X1 = *(const float4*)(xrow + base + ak + 4);
            X2 = *(const float4*)(xrow + base + ak + 32);
            X3 = *(const float4*)(xrow + base + ak + 36);
        } else if (do_tail) {
            // BK12 tail: k 768..799 valid (< 784), 800..831 OOB -> zero
            const int g0 = 768 + ak;
            X0 = (g0     < FIN) ? *(const float4*)(xrow + g0)     : make_float4(0.f,0.f,0.f,0.f);
            X1 = (g0 + 4 < FIN) ? *(const float4*)(xrow + g0 + 4) : make_float4(0.f,0.f,0.f,0.f);
            X2 = make_float4(0.f,0.f,0.f,0.f);
            X3 = make_float4(0.f,0.f,0.f,0.f);
        }
        // (4) compute BK j: 2 sub-chunks x 16 MFMA
        {
            const unsigned short* ab = Abuf[j & 1];
            bf16x8 afr[4];
#pragma unroll
            for (int mt = 0; mt < 4; ++mt)
                afr[mt] = *(const bf16x8*)&ab[(mt * 16 + lr) * AP2 + quad * 8];
#pragma unroll
            for (int mt = 0; mt < 4; ++mt)
#pragma unroll
                for (int nt = 0; nt < 4; ++nt)
                    acc[mt][nt] = __builtin_amdgcn_mfma_f32_16x16x32_bf16(afr[mt], bcur[nt], acc[mt][nt], 0, 0, 0);
#pragma unroll
            for (int mt = 0; mt < 4; ++mt)
                afr[mt] = *(const bf16x8*)&ab[(mt * 16 + lr) * AP2 + 32 + quad * 8];
#pragma unroll
            for (int mt = 0; mt < 4; ++mt)
#pragma unroll
                for (int nt = 0; nt < 4; ++nt)
                    acc[mt][nt] = __builtin_amdgcn_mfma_f32_16x16x32_bf16(afr[mt], bcur[nt + 4], acc[mt][nt], 0, 0, 0);
        }
#pragma unroll
        for (int q = 0; q < 8; ++q) bcur[q] = bnxt[q];
        __syncthreads();
    };

    // =================== layer 1: K = 800 = 12*64 + 32 ===================
    float4 xa0, xa1, xa2, xa3, xb0, xb1, xb2, xb3;
    // load + stage BK0 (k 0..63, all in-bounds)
    xa0 = *(const float4*)(xrow + ak);
    xa1 = *(const float4*)(xrow + ak + 4);
    xa2 = *(const float4*)(xrow + ak + 32);
    xa3 = *(const float4*)(xrow + ak + 36);
    {
        bf16x8 v0, v1;
        v0[0]=(short)f2bf(xa0.x); v0[1]=(short)f2bf(xa0.y); v0[2]=(short)f2bf(xa0.z); v0[3]=(short)f2bf(xa0.w);
        v0[4]=(short)f2bf(xa1.x); v0[5]=(short)f2bf(xa1.y); v0[6]=(short)f2bf(xa1.z); v0[7]=(short)f2bf(xa1.w);
        v1[0]=(short)f2bf(xa2.x); v1[1]=(short)f2bf(xa2.y); v1[2]=(short)f2bf(xa2.z); v1[3]=(short)f2bf(xa2.w);
        v1[4]=(short)f2bf(xa3.x); v1[5]=(short)f2bf(xa3.y); v1[6]=(short)f2bf(xa3.z); v1[7]=(short)f2bf(xa3.w);
        *(bf16x8*)&Abuf[0][ldsw]      = v0;
        *(bf16x8*)&Abuf[0][ldsw + 32] = v1;
    }
    // prefetch BK1 -> set A, BK2 -> set B (k 64..191, all in-bounds)
    xa0 = *(const float4*)(xrow + 64 + ak);
    xa1 = *(const float4*)(xrow + 64 + ak + 4);
    xa2 = *(const float4*)(xrow + 64 + ak + 32);
    xa3 = *(const float4*)(xrow + 64 + ak + 36);
    xb0 = *(const float4*)(xrow + 128 + ak);
    xb1 = *(const float4*)(xrow + 128 + ak + 4);
    xb2 = *(const float4*)(xrow + 128 + ak + 32);
    xb3 = *(const float4*)(xrow + 128 + ak + 36);
    // B chunks 0,1
#pragma unroll
    for (int nt = 0; nt < 4; ++nt) {
        bcur[nt]     = *(const bf16x8*)(b1base + nt * 16 * KP1);
        bcur[nt + 4] = *(const bf16x8*)(b1base + nt * 16 * KP1 + 32);
    }
    __syncthreads();

    // 12 intervals = 6 pairs: even j uses set A, odd j uses set B.
    //   even j in {0,2,4,6,8,10}: reload for j<=8 (BK j+3 <= BK11, in-bounds)
    //   odd  j in {1,3,5,7,9,11}: reload for j<=7; j==9 loads BK12 tail
#pragma unroll 1
    for (int jj = 0; jj < 6; ++jj) {
        const int j0 = 2 * jj;
        const int j1 = 2 * jj + 1;
        l1_interval(j0, xa0, xa1, xa2, xa3, j0 <= 8, false);
        l1_interval(j1, xb0, xb1, xb2, xb3, j1 <= 7, j1 == 9);
    }
    // tail: BK12 (chunk 24) from Abuf[0] (12&1==0), B in bcur[0..3]
    {
        bf16x8 afr[4];
#pragma unroll
        for (int mt = 0; mt < 4; ++mt)
            afr[mt] = *(const bf16x8*)&Abuf[0][(mt * 16 + lr) * AP2 + quad * 8];
#pragma unroll
        for (int mt = 0; mt < 4; ++mt)
#pragma unroll
            for (int nt = 0; nt < 4; ++nt)
                acc[mt][nt] = __builtin_amdgcn_mfma_f32_16x16x32_bf16(afr[mt], bcur[nt], acc[mt][nt], 0, 0, 0);
    }

    // prefetch first B2 chunk (latency hides under VALU epilogue)
    const unsigned short* b2base = W2t + ((size_t)ms * 256 + w * 64 + lr) * 256 + quad * 8;
#pragma unroll
    for (int nt = 0; nt < 4; ++nt)
        bcur[nt] = *(const bf16x8*)(b2base + nt * 16 * 256);

    // epilogue 1: bias + relu -> Hbuf (bf16), reset acc
#pragma unroll
    for (int mt = 0; mt < 4; ++mt)
#pragma unroll
        for (int nt = 0; nt < 4; ++nt) {
            int col = w * 64 + nt * 16 + lr;
            float bb = bias1s[col];
#pragma unroll
            for (int r = 0; r < 4; ++r) {
                int row = mt * 16 + quad * 4 + r;
                float v = acc[mt][nt][r] + bb;
                v = fmaxf(v, 0.f);
                Hbuf[row * HPITCH + col] = f2bf(v);
                acc[mt][nt][r] = 0.f;
            }
        }
    __syncthreads();

    // =================== layer 2: K = 256 (8 chunks) — barrier-free ===================
#pragma unroll
    for (int kc = 0; kc < 8; ++kc) {
        const int k0 = kc * 32;
        {
            const int koff_n = (kc < 7) ? (kc + 1) * 32 : 0;
#pragma unroll
            for (int nt = 0; nt < 4; ++nt)
                bnxt[nt] = *(const bf16x8*)(b2base + nt * 16 * 256 + koff_n);
        }
        bf16x8 afr[4];
#pragma unroll
        for (int mt = 0; mt < 4; ++mt)
            afr[mt] = *(const bf16x8*)&Hbuf[(mt * 16 + lr) * HPITCH + k0 + quad * 8];
#pragma unroll
        for (int mt = 0; mt < 4; ++mt)
#pragma unroll
            for (int nt = 0; nt < 4; ++nt)
                acc[mt][nt] = __builtin_amdgcn_mfma_f32_16x16x32_bf16(afr[mt], bcur[nt], acc[mt][nt], 0, 0, 0);
#pragma unroll
        for (int nt = 0; nt < 4; ++nt) bcur[nt] = bnxt[nt];
    }
    __syncthreads();   // all Hbuf reads done before overwrite

    // epilogue 2: bias + relu -> Hbuf (h2)
#pragma unroll
    for (int mt = 0; mt < 4; ++mt)
#pragma unroll
        for (int nt = 0; nt < 4; ++nt) {
            int col = w * 64 + nt * 16 + lr;
            float bb = bias2s[col];
#pragma unroll
            for (int r = 0; r < 4; ++r) {
                int row = mt * 16 + quad * 4 + r;
                float v = acc[mt][nt][r] + bb;
                v = fmaxf(v, 0.f);
                Hbuf[row * HPITCH + col] = f2bf(v);
            }
        }
    __syncthreads();

    // layer 3: h2[64x256] @ W3[256x3]
    if (t < 192) {
        int row = t & 63;
        int o   = t >> 6;
        float a3 = b3s[o];
        for (int j = 0; j < 256; j += 8) {
            u16x8 hv = *(const u16x8*)&Hbuf[row * HPITCH + j];
#pragma unroll
            for (int jj = 0; jj < 8; ++jj)
                a3 += bf2f(hv[jj]) * W3s[(j + jj) * 3 + o];
        }
        yws[(size_t)(b0 + row) * 12 + s * 3 + o] = a3;
    }
}

__global__ void tail_kernel(const float* __restrict__ yws,
                            const float* __restrict__ inp1, const float* __restrict__ loc1,
                            const float* __restrict__ inp2, const float* __restrict__ loc2,
                            const float* __restrict__ inp3,
                            const float* __restrict__ Wm1, const float* __restrict__ bm1,
                            const float* __restrict__ Wm2, const float* __restrict__ bm2,
                            float* __restrict__ out)
{
    int b = blockIdx.x * 256 + threadIdx.x;
    float xv[12];
    const float* p = yws + (size_t)b * 12;
#pragma unroll
    for (int i = 0; i < 12; ++i) xv[i] = p[i];
    float o2[2];
    scalar_tail(xv, inp1, loc1, inp2, loc2, inp3, Wm1, bm1, Wm2, bm2, o2);
    out[(size_t)b * 2 + 0] = o2[0];
    out[(size_t)b * 2 + 1] = o2[1];
}

// ============================================================
// PATH B: zero-workspace fully-fused fallback (unchanged)
// ============================================================
#define BPITCH 40
__global__ __launch_bounds__(256, 1) void fused_all_kernel(
    const float* __restrict__ x,
    const float* __restrict__ inp0, const float* __restrict__ loc0,
    const float* __restrict__ Wi1, const float* __restrict__ bi1,
    const float* __restrict__ Wi2, const float* __restrict__ bi2,
    const float* __restrict__ Wi3, const float* __restrict__ bi3,
    const float* __restrict__ inp1, const float* __restrict__ loc1,
    const float* __restrict__ inp2, const float* __restrict__ loc2,
    const float* __restrict__ inp3,
    const float* __restrict__ Wm1, const float* __restrict__ bm1,
    const float* __restrict__ Wm2, const float* __restrict__ bm2,
    float* __restrict__ out)
{
    __shared__ __align__(16) unsigned short Abuf[64 * APITCH];
    __shared__ __align__(16) unsigned short Bbuf[256 * BPITCH];
    __shared__ __align__(16) unsigned short Hbuf[64 * HPITCH];
    __shared__ float bias1s[256];
    __shared__ float bias2s[256];
    __shared__ float W3s[768];
    __shared__ float b3s[3];

    const int t  = threadIdx.x;
    const int b0 = blockIdx.x * 64;
    const int w    = t >> 6;
    const int l    = t & 63;
    const int quad = l >> 4;
    const int lr   = l & 15;
    const int ar = t >> 2;
    const int ak = (t & 3) * 8;
    const int wk  = t & 31;
    const int wn0 = (t >> 5) * 32;

    float yreg[4];

#pragma unroll 1
    for (int s = 0; s < 4; ++s) {
        int cs = 0; { float bv = inp0[s];
            for (int c = 1; c < CIN; ++c) { float v = inp0[c * S0 + s]; if (v > bv) { bv = v; cs = c; } } }
        int ms = 0; { float bv = loc0[s];
            for (int m = 1; m < 8; ++m) { float v = loc0[m * S0 + s]; if (v > bv) { bv = v; ms = m; } } }

        __syncthreads();
        bias1s[t] = bi1[ms * 256 + t];
        bias2s[t] = bi2[ms * 256 + t];
        W3s[t * 3 + 0] = Wi3[((size_t)ms * 256 + t) * 3 + 0];
        W3s[t * 3 + 1] = Wi3[((size_t)ms * 256 + t) * 3 + 1];
        W3s[t * 3 + 2] = Wi3[((size_t)ms * 256 + t) * 3 + 2];
        if (t < 3) b3s[t] = bi3[ms * 3 + t];

        f32x4 acc[4][4];
#pragma unroll
        for (int i = 0; i < 4; ++i)
#pragma unroll
            for (int j = 0; j < 4; ++j) acc[i][j] = (f32x4){0.f, 0.f, 0.f, 0.f};

        const float* xbase = x + ((size_t)b0 * CIN + cs) * FIN;
        const float* w1m   = Wi1 + (size_t)ms * FIN * 256;

        for (int kc = 0; kc < 25; ++kc) {
            const int k0 = kc * 32;
            {
                int gk = k0 + ak;
                bf16x8 av;
                if (gk < FIN) {
                    const float* p = xbase + (size_t)ar * (CIN * FIN) + gk;
                    float4 f0 = *(const float4*)(p);
                    float4 f1 = *(const float4*)(p + 4);
                    av[0] = (short)f2bf(f0.x); av[1] = (short)f2bf(f0.y);
                    av[2] = (short)f2bf(f0.z); av[3] = (short)f2bf(f0.w);
                    av[4] = (short)f2bf(f1.x); av[5] = (short)f2bf(f1.y);
                    av[6] = (short)f2bf(f1.z); av[7] = (short)f2bf(f1.w);
                } else {
                    av = (bf16x8){0,0,0,0,0,0,0,0};
                }
                *(bf16x8*)&Abuf[ar * APITCH + ak] = av;
            }
            {
                int gk = k0 + wk;
                if (gk < FIN) {
                    const float* wp = w1m + (size_t)gk * 256 + wn0;
#pragma unroll
                    for (int i = 0; i < 32; i += 4) {
                        float4 f = *(const float4*)(wp + i);
                        Bbuf[(wn0 + i + 0) * BPITCH + wk] = f2bf(f.x);
                        Bbuf[(wn0 + i + 1) * BPITCH + wk] = f2bf(f.y);
                        Bbuf[(wn0 + i + 2) * BPITCH + wk] = f2bf(f.z);
                        Bbuf[(wn0 + i + 3) * BPITCH + wk] = f2bf(f.w);
                    }
                } else {
#pragma unroll
                    for (int i = 0; i < 32; ++i)
                        Bbuf[(wn0 + i) * BPITCH + wk] = 0;
                }
            }
            __syncthreads();

            bf16x8 afr[4], bfr[4];
#pragma unroll
            for (int mt = 0; mt < 4; ++mt)
                afr[mt] = *(const bf16x8*)&Abuf[(mt * 16 + lr) * APITCH + quad * 8];
#pragma unroll
            for (int nt = 0; nt < 4; ++nt)
                bfr[nt] = *(const bf16x8*)&Bbuf[(w * 64 + nt * 16 + lr) * BPITCH + quad * 8];
#pragma unroll
            for (int mt = 0; mt < 4; ++mt)
#pragma unroll
                for (int nt = 0; nt < 4; ++nt)
                    acc[mt][nt] = __builtin_amdgcn_mfma_f32_16x16x32_bf16(afr[mt], bfr[nt], acc[mt][nt], 0, 0, 0);
            __syncthreads();
        }

#pragma unroll
        for (int mt = 0; mt < 4; ++mt)
#pragma unroll
            for (int nt = 0; nt < 4; ++nt) {
                int col = w * 64 + nt * 16 + lr;
                float bb = bias1s[col];
#pragma unroll
                for (int r = 0; r < 4; ++r) {
                    int row = mt * 16 + quad * 4 + r;
                    float v = acc[mt][nt][r] + bb;
                    v = fmaxf(v, 0.f);
                    Hbuf[row * HPITCH + col] = f2bf(v);
                    acc[mt][nt][r] = 0.f;
                }
            }
        __syncthreads();

        const float* w2m = Wi2 + (size_t)ms * 256 * 256;
        for (int kc = 0; kc < 8; ++kc) {
            const int k0 = kc * 32;
            {
                const float* wp = w2m + (size_t)(k0 + wk) * 256 + wn0;
#pragma unroll
                for (int i = 0; i < 32; i += 4) {
                    float4 f = *(const float4*)(wp + i);
                    Bbuf[(wn0 + i + 0) * BPITCH + wk] = f2bf(f.x);
                    Bbuf[(wn0 + i + 1) * BPITCH + wk] = f2bf(f.y);
                    Bbuf[(wn0 + i + 2) * BPITCH + wk] = f2bf(f.z);
                    Bbuf[(wn0 + i + 3) * BPITCH + wk] = f2bf(f.w);
                }
            }
            __syncthreads();

            bf16x8 afr[4], bfr[4];
#pragma unroll
            for (int mt = 0; mt < 4; ++mt)
                afr[mt] = *(const bf16x8*)&Hbuf[(mt * 16 + lr) * HPITCH + k0 + quad * 8];
#pragma unroll
            for (int nt = 0; nt < 4; ++nt)
                bfr[nt] = *(const bf16x8*)&Bbuf[(w * 64 + nt * 16 + lr) * BPITCH + quad * 8];
#pragma unroll
            for (int mt = 0; mt < 4; ++mt)
#pragma unroll
                for (int nt = 0; nt < 4; ++nt)
                    acc[mt][nt] = __builtin_amdgcn_mfma_f32_16x16x32_bf16(afr[mt], bfr[nt], acc[mt][nt], 0, 0, 0);
            __syncthreads();
        }

#pragma unroll
        for (int mt = 0; mt < 4; ++mt)
#pragma unroll
            for (int nt = 0; nt < 4; ++nt) {
                int col = w * 64 + nt * 16 + lr;
                float bb = bias2s[col];
#pragma unroll
                for (int r = 0; r < 4; ++r) {
                    int row = mt * 16 + quad * 4 + r;
                    float v = acc[mt][nt][r] + bb;
                    v = fmaxf(v, 0.f);
                    Hbuf[row * HPITCH + col] = f2bf(v);
                }
            }
        __syncthreads();

        if (t < 192) {
            int row = t & 63;
            int o   = t >> 6;
            float a3 = b3s[o];
            for (int j = 0; j < 256; j += 8) {
                u16x8 hv = *(const u16x8*)&Hbuf[row * HPITCH + j];
#pragma unroll
                for (int jj = 0; jj < 8; ++jj)
                    a3 += bf2f(hv[jj]) * W3s[(j + jj) * 3 + o];
            }
            yreg[s] = a3;
        }
    }

    __syncthreads();
    float* ybuf = (float*)Abuf;
    if (t < 192) {
        int row = t & 63;
        int o   = t >> 6;
#pragma unroll
        for (int s = 0; s < 4; ++s)
            ybuf[row * 12 + s * 3 + o] = yreg[s];
    }
    __syncthreads();
    if (t < 64) {
        float xv[12];
#pragma unroll
        for (int i = 0; i < 12; ++i) xv[i] = ybuf[t * 12 + i];
        float o2[2];
        scalar_tail(xv, inp1, loc1, inp2, loc2, inp3, Wm1, bm1, Wm2, bm2, o2);
        out[(size_t)(b0 + t) * 2 + 0] = o2[0];
        out[(size_t)(b0 + t) * 2 + 1] = o2[1];
    }
}

// ---------------- launcher ----------------
extern "C" void kernel_launch(void* const* d_in, const int* in_sizes, int n_in,
                              void* d_out, int out_size, void* d_ws, size_t ws_size,
                              hipStream_t stream) {
    if (n_in < 18) return;
    const float* x    = (const float*)d_in[0];
    const float* inp0 = (const float*)d_in[1];
    const float* loc0 = (const float*)d_in[2];
    const float* inp1 = (const float*)d_in[3];
    const float* loc1 = (const float*)d_in[4];
    const float* inp2 = (const float*)d_in[5];
    const float* loc2 = (const float*)d_in[6];
    const float* inp3 = (const float*)d_in[7];
    const float* Wi1  = (const float*)d_in[8];
    const float* bi1  = (const float*)d_in[9];
    const float* Wi2  = (const float*)d_in[10];
    const float* bi2  = (const float*)d_in[11];
    const float* Wi3  = (const float*)d_in[12];
    const float* bi3  = (const float*)d_in[13];
    const float* Wm1  = (const float*)d_in[14];
    const float* bm1  = (const float*)d_in[15];
    const float* Wm2  = (const float*)d_in[16];
    const float* bm2  = (const float*)d_in[17];
    float* out = (float*)d_out;

    if (ws_size >= WS_NEED && d_ws != nullptr) {
        unsigned short* W1t = (unsigned short*)((char*)d_ws + W1T_OFF);
        unsigned short* W2t = (unsigned short*)((char*)d_ws + W2T_OFF);
        float*          yws = (float*)((char*)d_ws + YWS_OFF);

        prep_weights_kernel<<<2112, 256, 0, stream>>>(Wi1, Wi2, W1t, W2t);
        img_gemm_kernel<<<512, 256, 0, stream>>>(x, inp0, loc0, W1t, W2t, bi1, bi2, Wi3, bi3, yws);
        tail_kernel<<<BATCH / 256, 256, 0, stream>>>(yws, inp1, loc1, inp2, loc2, inp3,
                                                     Wm1, bm1, Wm2, bm2, out);
    } else {
        fused_all_kernel<<<BATCH / 64, 256, 0, stream>>>(
            x, inp0, loc0, Wi1, bi1, Wi2, bi2, Wi3, bi3,
            inp1, loc1, inp2, loc2, inp3, Wm1, bm1, Wm2, bm2, out);
    }
}

// Round 11
// 322.074 us; speedup vs baseline: 1.0117x; 1.0036x over previous
//
#include <hip/hip_runtime.h>
#include <hip/hip_bf16.h>
#include <stdint.h>

// ---------------- types ----------------
typedef __attribute__((ext_vector_type(8))) short  bf16x8;
typedef __attribute__((ext_vector_type(4))) float  f32x4;
typedef __attribute__((ext_vector_type(8))) unsigned short u16x8;

__device__ __forceinline__ unsigned short f2bf(float f) {
    union { float f; uint32_t u; } v; v.f = f;
    uint32_t u = v.u;
    uint32_t r = (u + 0x7FFFu + ((u >> 16) & 1u)) >> 16;
    return (unsigned short)r;
}
__device__ __forceinline__ float bf2f(unsigned short h) {
    union { uint32_t u; float f; } v; v.u = ((uint32_t)h) << 16;
    return v.f;
}

// ---------------- constants ----------------
#define BATCH 8192
#define CIN   8
#define S0    4
#define FIN   784
#define KP1   800      // FIN padded to 25*32
#define HDIM  256
#define APITCH 40      // Path B A-tile pitch (32 + 8 pad)
#define AP2   104      // BK=64 A-tile pitch: 64 + 40 pad; 52 dwords == 20 mod 32
                       // -> identical (free, 2-way) bank pattern to APITCH=40
#define HPITCH 264     // 256 + 8 pad (shorts)

// ws layout (bytes) for fast path
#define W1T_OFF 0
#define W1T_BYTES (8u * 256u * 800u * 2u)          // 3,276,800
#define W2T_OFF (W1T_OFF + W1T_BYTES)
#define W2T_BYTES (8u * 256u * 256u * 2u)          // 1,048,576
#define YWS_OFF (W2T_OFF + W2T_BYTES)              // 4,325,376
#define WS_NEED (YWS_OFF + (size_t)BATCH * 12u * 4u)  // 4,718,592

// ============================================================
// scalar-tail math shared by both paths
// ============================================================
__device__ __forceinline__ void scalar_tail(const float* xv,  // [12]
    const float* __restrict__ inp1, const float* __restrict__ loc1,
    const float* __restrict__ inp2, const float* __restrict__ loc2,
    const float* __restrict__ inp3,
    const float* __restrict__ Wm1, const float* __restrict__ bm1,
    const float* __restrict__ Wm2, const float* __restrict__ bm2,
    float* out2)
{
    float xv1[3];
#pragma unroll
    for (int s = 0; s < 3; ++s) {
        int i1 = 0, i2 = 0; float b1v = inp1[s], b2v = -3.0e38f;
        for (int d = 1; d < 12; ++d) {
            float v = inp1[d * 3 + s];
            if (v > b1v)      { b2v = b1v; i2 = i1; b1v = v; i1 = d; }
            else if (v > b2v) { b2v = v; i2 = d; }
        }
        int m = (loc1[3 + s] > loc1[s]) ? 1 : 0;
        float v1 = xv[i1], v2 = xv[i2];
        float o = bm2[m];
#pragma unroll
        for (int j = 0; j < 12; ++j) {
            float h = v1 * Wm1[(m * 2 + 0) * 12 + j] + v2 * Wm1[(m * 2 + 1) * 12 + j] + bm1[m * 12 + j];
            h = fmaxf(h, 0.f);
            o += h * Wm2[m * 12 + j];
        }
        xv1[s] = o;
    }
    float xv2[2];
#pragma unroll
    for (int s = 0; s < 2; ++s) {
        int i1 = 0, i2 = 0; float b1v = inp2[s], b2v = -3.0e38f;
        for (int d = 1; d < 3; ++d) {
            float v = inp2[d * 2 + s];
            if (v > b1v)      { b2v = b1v; i2 = i1; b1v = v; i1 = d; }
            else if (v > b2v) { b2v = v; i2 = d; }
        }
        int m = (loc2[2 + s] > loc2[s]) ? 1 : 0;
        float v1 = xv1[i1], v2 = xv1[i2];
        float o = bm2[m];
#pragma unroll
        for (int j = 0; j < 12; ++j) {
            float h = v1 * Wm1[(m * 2 + 0) * 12 + j] + v2 * Wm1[(m * 2 + 1) * 12 + j] + bm1[m * 12 + j];
            h = fmaxf(h, 0.f);
            o += h * Wm2[m * 12 + j];
        }
        xv2[s] = o;
    }
    int j1 = (inp3[1] > inp3[0]) ? 1 : 0;
    int j2 = 1 - j1;
    out2[0] = 1.f / (1.f + expf(-xv2[j1]));
    out2[1] = 1.f / (1.f + expf(-xv2[j2]));
}

// ============================================================
// PATH A kernels
// ============================================================
// merged prep: blocks [0,1600) -> Wi1 transpose; [1600,2112) -> Wi2
__global__ void prep_weights_kernel(const float* __restrict__ Wi1, const float* __restrict__ Wi2,
                                    unsigned short* __restrict__ W1t, unsigned short* __restrict__ W2t)
{
    __shared__ float tile[32][33];
    int bx = blockIdx.x;
    const float* src; unsigned short* dst; int K, Kpad, N, ktiles, ntiles;
    if (bx < 1600) { src = Wi1; dst = W1t; K = 784; Kpad = 800; N = 256; ktiles = 25; ntiles = 8; }
    else { bx -= 1600; src = Wi2; dst = W2t; K = 256; Kpad = 256; N = 256; ktiles = 8; ntiles = 8; }

    int nt = bx % ntiles;
    int kt = (bx / ntiles) % ktiles;
    int m  = bx / (ntiles * ktiles);
    int k0 = kt * 32, n0 = nt * 32;
    int t = threadIdx.x;
    int r  = t >> 3;
    int c4 = (t & 7) * 4;

    float4 v = make_float4(0.f, 0.f, 0.f, 0.f);
    if (k0 + r < K)
        v = *(const float4*)(src + ((size_t)m * K + (k0 + r)) * N + n0 + c4);
    tile[r][c4 + 0] = v.x; tile[r][c4 + 1] = v.y;
    tile[r][c4 + 2] = v.z; tile[r][c4 + 3] = v.w;
    __syncthreads();

    int nr = r, kc = c4;
    ushort4 ov;
    ov.x = f2bf(tile[kc + 0][nr]);
    ov.y = f2bf(tile[kc + 1][nr]);
    ov.z = f2bf(tile[kc + 2][nr]);
    ov.w = f2bf(tile[kc + 3][nr]);
    *(ushort4*)(dst + ((size_t)m * N + n0 + nr) * Kpad + k0 + kc) = ov;
}

// main fused img-level kernel v8 = v7 (BK=64, depth-2 x prefetch, slot-major
// XCD map) + RAW IN-LOOP BARRIERS: __syncthreads() forces a full
// s_waitcnt vmcnt(0) drain, which completes the just-issued x/B prefetches at
// EVERY interval boundary (~600 cy exposed; this is why depth-2 was neutral).
// Replace the 12 in-interval barriers with {s_waitcnt lgkmcnt(0); s_barrier}:
// LDS ordering (the only cross-wave hazard) is preserved; global loads stay
// in flight across the barrier and are consumed later through registers with
// compiler-tracked vmcnt(N) waits (depth-2 gives x-loads 2 intervals ~1200cy).
__global__ __launch_bounds__(256, 1) void img_gemm_kernel(
    const float* __restrict__ x,
    const float* __restrict__ inp0, const float* __restrict__ loc0,
    const unsigned short* __restrict__ W1t, const unsigned short* __restrict__ W2t,
    const float* __restrict__ bi1, const float* __restrict__ bi2,
    const float* __restrict__ Wi3, const float* __restrict__ bi3,
    float* __restrict__ yws)
{
    __shared__ __align__(16) unsigned short Abuf[2][64 * AP2];
    __shared__ __align__(16) unsigned short Hbuf[64 * HPITCH];
    __shared__ float bias1s[256];
    __shared__ float bias2s[256];
    __shared__ float W3s[768];
    __shared__ float b3s[3];

    const int t  = threadIdx.x;
    const int bx = blockIdx.x;
    const int s  = (bx & 7) >> 1;                 // XCD pair -> one slot
    const int rt = ((bx >> 3) << 1) | (bx & 1);   // 0..127
    const int b0 = rt * 64;

    // routing (straight-through forward == hard argmax)
    int cs = 0; { float bv = inp0[s];
        for (int c = 1; c < CIN; ++c) { float v = inp0[c * S0 + s]; if (v > bv) { bv = v; cs = c; } } }
    int ms = 0; { float bv = loc0[s];
        for (int m = 1; m < 8; ++m) { float v = loc0[m * S0 + s]; if (v > bv) { bv = v; ms = m; } } }

    // stage biases / W3 (covered by the prologue barrier)
    bias1s[t] = bi1[ms * 256 + t];
    bias2s[t] = bi2[ms * 256 + t];
    W3s[t * 3 + 0] = Wi3[((size_t)ms * 256 + t) * 3 + 0];
    W3s[t * 3 + 1] = Wi3[((size_t)ms * 256 + t) * 3 + 1];
    W3s[t * 3 + 2] = Wi3[((size_t)ms * 256 + t) * 3 + 2];
    if (t < 3) b3s[t] = bi3[ms * 3 + t];

    const int w    = t >> 6;
    const int l    = t & 63;
    const int quad = l >> 4;
    const int lr   = l & 15;

    f32x4 acc[4][4];
#pragma unroll
    for (int i = 0; i < 4; ++i)
#pragma unroll
        for (int j = 0; j < 4; ++j) acc[i][j] = (f32x4){0.f, 0.f, 0.f, 0.f};

    // A staging coords: 64 rows x 64 k per BK-iter; per thread 16 floats
    const int ar = t >> 2;          // 0..63 (A row)
    const int ak = (t & 3) * 8;     // 0,8,16,24
    const float* xrow = x + ((size_t)(b0 + ar) * CIN + cs) * FIN;
    const int ldsw = ar * AP2 + ak;

    const unsigned short* b1base = W1t + ((size_t)ms * 256 + w * 64 + lr) * KP1 + quad * 8;

    bf16x8 bcur[8], bnxt[8];

    // one L1 interval: B prefetch -> stage BK j+1 from X regs -> optional x
    // reload of BK j+3 into the SAME X regs -> 32 MFMA on BK j -> raw barrier.
    auto l1_interval = [&](int j, float4& X0, float4& X1, float4& X2, float4& X3,
                           bool do_load, bool do_tail) {
        // (1) B prefetch for next BK-iter (L2-hot panel)
        const int c0 = (j < 11) ? (2 * j + 2) * 32 : 768;   // j==11: tail chunk 24
        const int c1 = (j < 11) ? (2 * j + 3) * 32 : 0;     // j==11: dummy
#pragma unroll
        for (int nt = 0; nt < 4; ++nt) {
            bnxt[nt]     = *(const bf16x8*)(b1base + nt * 16 * KP1 + c0);
            bnxt[nt + 4] = *(const bf16x8*)(b1base + nt * 16 * KP1 + c1);
        }
        // (2) stage BK j+1 from X regs (loaded 2 intervals ago)
        {
            unsigned short* abn = Abuf[(j + 1) & 1];
            bf16x8 v0, v1;
            v0[0]=(short)f2bf(X0.x); v0[1]=(short)f2bf(X0.y); v0[2]=(short)f2bf(X0.z); v0[3]=(short)f2bf(X0.w);
            v0[4]=(short)f2bf(X1.x); v0[5]=(short)f2bf(X1.y); v0[6]=(short)f2bf(X1.z); v0[7]=(short)f2bf(X1.w);
            v1[0]=(short)f2bf(X2.x); v1[1]=(short)f2bf(X2.y); v1[2]=(short)f2bf(X2.z); v1[3]=(short)f2bf(X2.w);
            v1[4]=(short)f2bf(X3.x); v1[5]=(short)f2bf(X3.y); v1[6]=(short)f2bf(X3.z); v1[7]=(short)f2bf(X3.w);
            *(bf16x8*)&abn[ldsw]      = v0;
            *(bf16x8*)&abn[ldsw + 32] = v1;
        }
        // (3) reload X regs with BK j+3 (consumed at interval j+2)
        if (do_load) {
            const int base = (j + 3) * 64;   // j+3 <= 11 -> all k < 768+64, in-bounds
            X0 = *(const float4*)(xrow + base + ak);
            X1 = *(const float4*)(xrow + base + ak + 4);
            X2 = *(const float4*)(xrow + base + ak + 32);
            X3 = *(const float4*)(xrow + base + ak + 36);
        } else if (do_tail) {
            // BK12 tail: k 768..799 valid (< 784), 800..831 OOB -> zero
            const int g0 = 768 + ak;
            X0 = (g0     < FIN) ? *(const float4*)(xrow + g0)     : make_float4(0.f,0.f,0.f,0.f);
            X1 = (g0 + 4 < FIN) ? *(const float4*)(xrow + g0 + 4) : make_float4(0.f,0.f,0.f,0.f);
            X2 = make_float4(0.f,0.f,0.f,0.f);
            X3 = make_float4(0.f,0.f,0.f,0.f);
        }
        // (4) compute BK j: 2 sub-chunks x 16 MFMA
        {
            const unsigned short* ab = Abuf[j & 1];
            bf16x8 afr[4];
#pragma unroll
            for (int mt = 0; mt < 4; ++mt)
                afr[mt] = *(const bf16x8*)&ab[(mt * 16 + lr) * AP2 + quad * 8];
#pragma unroll
            for (int mt = 0; mt < 4; ++mt)
#pragma unroll
                for (int nt = 0; nt < 4; ++nt)
                    acc[mt][nt] = __builtin_amdgcn_mfma_f32_16x16x32_bf16(afr[mt], bcur[nt], acc[mt][nt], 0, 0, 0);
#pragma unroll
            for (int mt = 0; mt < 4; ++mt)
                afr[mt] = *(const bf16x8*)&ab[(mt * 16 + lr) * AP2 + 32 + quad * 8];
#pragma unroll
            for (int mt = 0; mt < 4; ++mt)
#pragma unroll
                for (int nt = 0; nt < 4; ++nt)
                    acc[mt][nt] = __builtin_amdgcn_mfma_f32_16x16x32_bf16(afr[mt], bcur[nt + 4], acc[mt][nt], 0, 0, 0);
        }
#pragma unroll
        for (int q = 0; q < 8; ++q) bcur[q] = bnxt[q];
        // raw barrier: LDS-ordered only, global loads stay in flight (no
        // vmcnt(0) drain -- the whole point of this round).
        asm volatile("s_waitcnt lgkmcnt(0)" ::: "memory");
        __builtin_amdgcn_s_barrier();
    };

    // =================== layer 1: K = 800 = 12*64 + 32 ===================
    float4 xa0, xa1, xa2, xa3, xb0, xb1, xb2, xb3;
    // load + stage BK0 (k 0..63, all in-bounds)
    xa0 = *(const float4*)(xrow + ak);
    xa1 = *(const float4*)(xrow + ak + 4);
    xa2 = *(const float4*)(xrow + ak + 32);
    xa3 = *(const float4*)(xrow + ak + 36);
    {
        bf16x8 v0, v1;
        v0[0]=(short)f2bf(xa0.x); v0[1]=(short)f2bf(xa0.y); v0[2]=(short)f2bf(xa0.z); v0[3]=(short)f2bf(xa0.w);
        v0[4]=(short)f2bf(xa1.x); v0[5]=(short)f2bf(xa1.y); v0[6]=(short)f2bf(xa1.z); v0[7]=(short)f2bf(xa1.w);
        v1[0]=(short)f2bf(xa2.x); v1[1]=(short)f2bf(xa2.y); v1[2]=(short)f2bf(xa2.z); v1[3]=(short)f2bf(xa2.w);
        v1[4]=(short)f2bf(xa3.x); v1[5]=(short)f2bf(xa3.y); v1[6]=(short)f2bf(xa3.z); v1[7]=(short)f2bf(xa3.w);
        *(bf16x8*)&Abuf[0][ldsw]      = v0;
        *(bf16x8*)&Abuf[0][ldsw + 32] = v1;
    }
    // prefetch BK1 -> set A, BK2 -> set B (k 64..191, all in-bounds)
    xa0 = *(const float4*)(xrow + 64 + ak);
    xa1 = *(const float4*)(xrow + 64 + ak + 4);
    xa2 = *(const float4*)(xrow + 64 + ak + 32);
    xa3 = *(const float4*)(xrow + 64 + ak + 36);
    xb0 = *(const float4*)(xrow + 128 + ak);
    xb1 = *(const float4*)(xrow + 128 + ak + 4);
    xb2 = *(const float4*)(xrow + 128 + ak + 32);
    xb3 = *(const float4*)(xrow + 128 + ak + 36);
    // B chunks 0,1
#pragma unroll
    for (int nt = 0; nt < 4; ++nt) {
        bcur[nt]     = *(const bf16x8*)(b1base + nt * 16 * KP1);
        bcur[nt + 4] = *(const bf16x8*)(b1base + nt * 16 * KP1 + 32);
    }
    __syncthreads();   // prologue: full drain once is fine

    // 12 intervals = 6 pairs: even j uses set A, odd j uses set B.
    //   even j in {0,2,4,6,8,10}: reload for j<=8 (BK j+3 <= BK11, in-bounds)
    //   odd  j in {1,3,5,7,9,11}: reload for j<=7; j==9 loads BK12 tail
#pragma unroll 1
    for (int jj = 0; jj < 6; ++jj) {
        const int j0 = 2 * jj;
        const int j1 = 2 * jj + 1;
        l1_interval(j0, xa0, xa1, xa2, xa3, j0 <= 8, false);
        l1_interval(j1, xb0, xb1, xb2, xb3, j1 <= 7, j1 == 9);
    }
    // tail: BK12 (chunk 24) from Abuf[0] (12&1==0), B in bcur[0..3]
    {
        bf16x8 afr[4];
#pragma unroll
        for (int mt = 0; mt < 4; ++mt)
            afr[mt] = *(const bf16x8*)&Abuf[0][(mt * 16 + lr) * AP2 + quad * 8];
#pragma unroll
        for (int mt = 0; mt < 4; ++mt)
#pragma unroll
            for (int nt = 0; nt < 4; ++nt)
                acc[mt][nt] = __builtin_amdgcn_mfma_f32_16x16x32_bf16(afr[mt], bcur[nt], acc[mt][nt], 0, 0, 0);
    }

    // prefetch first B2 chunk (latency hides under VALU epilogue)
    const unsigned short* b2base = W2t + ((size_t)ms * 256 + w * 64 + lr) * 256 + quad * 8;
#pragma unroll
    for (int nt = 0; nt < 4; ++nt)
        bcur[nt] = *(const bf16x8*)(b2base + nt * 16 * 256);

    // epilogue 1: bias + relu -> Hbuf (bf16), reset acc
#pragma unroll
    for (int mt = 0; mt < 4; ++mt)
#pragma unroll
        for (int nt = 0; nt < 4; ++nt) {
            int col = w * 64 + nt * 16 + lr;
            float bb = bias1s[col];
#pragma unroll
            for (int r = 0; r < 4; ++r) {
                int row = mt * 16 + quad * 4 + r;
                float v = acc[mt][nt][r] + bb;
                v = fmaxf(v, 0.f);
                Hbuf[row * HPITCH + col] = f2bf(v);
                acc[mt][nt][r] = 0.f;
            }
        }
    __syncthreads();

    // =================== layer 2: K = 256 (8 chunks) — barrier-free ===================
#pragma unroll
    for (int kc = 0; kc < 8; ++kc) {
        const int k0 = kc * 32;
        {
            const int koff_n = (kc < 7) ? (kc + 1) * 32 : 0;
#pragma unroll
            for (int nt = 0; nt < 4; ++nt)
                bnxt[nt] = *(const bf16x8*)(b2base + nt * 16 * 256 + koff_n);
        }
        bf16x8 afr[4];
#pragma unroll
        for (int mt = 0; mt < 4; ++mt)
            afr[mt] = *(const bf16x8*)&Hbuf[(mt * 16 + lr) * HPITCH + k0 + quad * 8];
#pragma unroll
        for (int mt = 0; mt < 4; ++mt)
#pragma unroll
            for (int nt = 0; nt < 4; ++nt)
                acc[mt][nt] = __builtin_amdgcn_mfma_f32_16x16x32_bf16(afr[mt], bcur[nt], acc[mt][nt], 0, 0, 0);
#pragma unroll
        for (int nt = 0; nt < 4; ++nt) bcur[nt] = bnxt[nt];
    }
    __syncthreads();   // all Hbuf reads done before overwrite

    // epilogue 2: bias + relu -> Hbuf (h2)
#pragma unroll
    for (int mt = 0; mt < 4; ++mt)
#pragma unroll
        for (int nt = 0; nt < 4; ++nt) {
            int col = w * 64 + nt * 16 + lr;
            float bb = bias2s[col];
#pragma unroll
            for (int r = 0; r < 4; ++r) {
                int row = mt * 16 + quad * 4 + r;
                float v = acc[mt][nt][r] + bb;
                v = fmaxf(v, 0.f);
                Hbuf[row * HPITCH + col] = f2bf(v);
            }
        }
    __syncthreads();

    // layer 3: h2[64x256] @ W3[256x3]
    if (t < 192) {
        int row = t & 63;
        int o   = t >> 6;
        float a3 = b3s[o];
        for (int j = 0; j < 256; j += 8) {
            u16x8 hv = *(const u16x8*)&Hbuf[row * HPITCH + j];
#pragma unroll
            for (int jj = 0; jj < 8; ++jj)
                a3 += bf2f(hv[jj]) * W3s[(j + jj) * 3 + o];
        }
        yws[(size_t)(b0 + row) * 12 + s * 3 + o] = a3;
    }
}

__global__ void tail_kernel(const float* __restrict__ yws,
                            const float* __restrict__ inp1, const float* __restrict__ loc1,
                            const float* __restrict__ inp2, const float* __restrict__ loc2,
                            const float* __restrict__ inp3,
                            const float* __restrict__ Wm1, const float* __restrict__ bm1,
                            const float* __restrict__ Wm2, const float* __restrict__ bm2,
                            float* __restrict__ out)
{
    int b = blockIdx.x * 256 + threadIdx.x;
    float xv[12];
    const float* p = yws + (size_t)b * 12;
#pragma unroll
    for (int i = 0; i < 12; ++i) xv[i] = p[i];
    float o2[2];
    scalar_tail(xv, inp1, loc1, inp2, loc2, inp3, Wm1, bm1, Wm2, bm2, o2);
    out[(size_t)b * 2 + 0] = o2[0];
    out[(size_t)b * 2 + 1] = o2[1];
}

// ============================================================
// PATH B: zero-workspace fully-fused fallback (unchanged)
// ============================================================
#define BPITCH 40
__global__ __launch_bounds__(256, 1) void fused_all_kernel(
    const float* __restrict__ x,
    const float* __restrict__ inp0, const float* __restrict__ loc0,
    const float* __restrict__ Wi1, const float* __restrict__ bi1,
    const float* __restrict__ Wi2, const float* __restrict__ bi2,
    const float* __restrict__ Wi3, const float* __restrict__ bi3,
    const float* __restrict__ inp1, const float* __restrict__ loc1,
    const float* __restrict__ inp2, const float* __restrict__ loc2,
    const float* __restrict__ inp3,
    const float* __restrict__ Wm1, const float* __restrict__ bm1,
    const float* __restrict__ Wm2, const float* __restrict__ bm2,
    float* __restrict__ out)
{
    __shared__ __align__(16) unsigned short Abuf[64 * APITCH];
    __shared__ __align__(16) unsigned short Bbuf[256 * BPITCH];
    __shared__ __align__(16) unsigned short Hbuf[64 * HPITCH];
    __shared__ float bias1s[256];
    __shared__ float bias2s[256];
    __shared__ float W3s[768];
    __shared__ float b3s[3];

    const int t  = threadIdx.x;
    const int b0 = blockIdx.x * 64;
    const int w    = t >> 6;
    const int l    = t & 63;
    const int quad = l >> 4;
    const int lr   = l & 15;
    const int ar = t >> 2;
    const int ak = (t & 3) * 8;
    const int wk  = t & 31;
    const int wn0 = (t >> 5) * 32;

    float yreg[4];

#pragma unroll 1
    for (int s = 0; s < 4; ++s) {
        int cs = 0; { float bv = inp0[s];
            for (int c = 1; c < CIN; ++c) { float v = inp0[c * S0 + s]; if (v > bv) { bv = v; cs = c; } } }
        int ms = 0; { float bv = loc0[s];
            for (int m = 1; m < 8; ++m) { float v = loc0[m * S0 + s]; if (v > bv) { bv = v; ms = m; } } }

        __syncthreads();
        bias1s[t] = bi1[ms * 256 + t];
        bias2s[t] = bi2[ms * 256 + t];
        W3s[t * 3 + 0] = Wi3[((size_t)ms * 256 + t) * 3 + 0];
        W3s[t * 3 + 1] = Wi3[((size_t)ms * 256 + t) * 3 + 1];
        W3s[t * 3 + 2] = Wi3[((size_t)ms * 256 + t) * 3 + 2];
        if (t < 3) b3s[t] = bi3[ms * 3 + t];

        f32x4 acc[4][4];
#pragma unroll
        for (int i = 0; i < 4; ++i)
#pragma unroll
            for (int j = 0; j < 4; ++j) acc[i][j] = (f32x4){0.f, 0.f, 0.f, 0.f};

        const float* xbase = x + ((size_t)b0 * CIN + cs) * FIN;
        const float* w1m   = Wi1 + (size_t)ms * FIN * 256;

        for (int kc = 0; kc < 25; ++kc) {
            const int k0 = kc * 32;
            {
                int gk = k0 + ak;
                bf16x8 av;
                if (gk < FIN) {
                    const float* p = xbase + (size_t)ar * (CIN * FIN) + gk;
                    float4 f0 = *(const float4*)(p);
                    float4 f1 = *(const float4*)(p + 4);
                    av[0] = (short)f2bf(f0.x); av[1] = (short)f2bf(f0.y);
                    av[2] = (short)f2bf(f0.z); av[3] = (short)f2bf(f0.w);
                    av[4] = (short)f2bf(f1.x); av[5] = (short)f2bf(f1.y);
                    av[6] = (short)f2bf(f1.z); av[7] = (short)f2bf(f1.w);
                } else {
                    av = (bf16x8){0,0,0,0,0,0,0,0};
                }
                *(bf16x8*)&Abuf[ar * APITCH + ak] = av;
            }
            {
                int gk = k0 + wk;
                if (gk < FIN) {
                    const float* wp = w1m + (size_t)gk * 256 + wn0;
#pragma unroll
                    for (int i = 0; i < 32; i += 4) {
                        float4 f = *(const float4*)(wp + i);
                        Bbuf[(wn0 + i + 0) * BPITCH + wk] = f2bf(f.x);
                        Bbuf[(wn0 + i + 1) * BPITCH + wk] = f2bf(f.y);
                        Bbuf[(wn0 + i + 2) * BPITCH + wk] = f2bf(f.z);
                        Bbuf[(wn0 + i + 3) * BPITCH + wk] = f2bf(f.w);
                    }
                } else {
#pragma unroll
                    for (int i = 0; i < 32; ++i)
                        Bbuf[(wn0 + i) * BPITCH + wk] = 0;
                }
            }
            __syncthreads();

            bf16x8 afr[4], bfr[4];
#pragma unroll
            for (int mt = 0; mt < 4; ++mt)
                afr[mt] = *(const bf16x8*)&Abuf[(mt * 16 + lr) * APITCH + quad * 8];
#pragma unroll
            for (int nt = 0; nt < 4; ++nt)
                bfr[nt] = *(const bf16x8*)&Bbuf[(w * 64 + nt * 16 + lr) * BPITCH + quad * 8];
#pragma unroll
            for (int mt = 0; mt < 4; ++mt)
#pragma unroll
                for (int nt = 0; nt < 4; ++nt)
                    acc[mt][nt] = __builtin_amdgcn_mfma_f32_16x16x32_bf16(afr[mt], bfr[nt], acc[mt][nt], 0, 0, 0);
            __syncthreads();
        }

#pragma unroll
        for (int mt = 0; mt < 4; ++mt)
#pragma unroll
            for (int nt = 0; nt < 4; ++nt) {
                int col = w * 64 + nt * 16 + lr;
                float bb = bias1s[col];
#pragma unroll
                for (int r = 0; r < 4; ++r) {
                    int row = mt * 16 + quad * 4 + r;
                    float v = acc[mt][nt][r] + bb;
                    v = fmaxf(v, 0.f);
                    Hbuf[row * HPITCH + col] = f2bf(v);
                    acc[mt][nt][r] = 0.f;
                }
            }
        __syncthreads();

        const float* w2m = Wi2 + (size_t)ms * 256 * 256;
        for (int kc = 0; kc < 8; ++kc) {
            const int k0 = kc * 32;
            {
                const float* wp = w2m + (size_t)(k0 + wk) * 256 + wn0;
#pragma unroll
                for (int i = 0; i < 32; i += 4) {
                    float4 f = *(const float4*)(wp + i);
                    Bbuf[(wn0 + i + 0) * BPITCH + wk] = f2bf(f.x);
                    Bbuf[(wn0 + i + 1) * BPITCH + wk] = f2bf(f.y);
                    Bbuf[(wn0 + i + 2) * BPITCH + wk] = f2bf(f.z);
                    Bbuf[(wn0 + i + 3) * BPITCH + wk] = f2bf(f.w);
                }
            }
            __syncthreads();

            bf16x8 afr[4], bfr[4];
#pragma unroll
            for (int mt = 0; mt < 4; ++mt)
                afr[mt] = *(const bf16x8*)&Hbuf[(mt * 16 + lr) * HPITCH + k0 + quad * 8];
#pragma unroll
            for (int nt = 0; nt < 4; ++nt)
                bfr[nt] = *(const bf16x8*)&Bbuf[(w * 64 + nt * 16 + lr) * BPITCH + quad * 8];
#pragma unroll
            for (int mt = 0; mt < 4; ++mt)
#pragma unroll
                for (int nt = 0; nt < 4; ++nt)
                    acc[mt][nt] = __builtin_amdgcn_mfma_f32_16x16x32_bf16(afr[mt], bfr[nt], acc[mt][nt], 0, 0, 0);
            __syncthreads();
        }

#pragma unroll
        for (int mt = 0; mt < 4; ++mt)
#pragma unroll
            for (int nt = 0; nt < 4; ++nt) {
                int col = w * 64 + nt * 16 + lr;
                float bb = bias2s[col];
#pragma unroll
                for (int r = 0; r < 4; ++r) {
                    int row = mt * 16 + quad * 4 + r;
                    float v = acc[mt][nt][r] + bb;
                    v = fmaxf(v, 0.f);
                    Hbuf[row * HPITCH + col] = f2bf(v);
                }
            }
        __syncthreads();

        if (t < 192) {
            int row = t & 63;
            int o   = t >> 6;
            float a3 = b3s[o];
            for (int j = 0; j < 256; j += 8) {
                u16x8 hv = *(const u16x8*)&Hbuf[row * HPITCH + j];
#pragma unroll
                for (int jj = 0; jj < 8; ++jj)
                    a3 += bf2f(hv[jj]) * W3s[(j + jj) * 3 + o];
            }
            yreg[s] = a3;
        }
    }

    __syncthreads();
    float* ybuf = (float*)Abuf;
    if (t < 192) {
        int row = t & 63;
        int o   = t >> 6;
#pragma unroll
        for (int s = 0; s < 4; ++s)
            ybuf[row * 12 + s * 3 + o] = yreg[s];
    }
    __syncthreads();
    if (t < 64) {
        float xv[12];
#pragma unroll
        for (int i = 0; i < 12; ++i) xv[i] = ybuf[t * 12 + i];
        float o2[2];
        scalar_tail(xv, inp1, loc1, inp2, loc2, inp3, Wm1, bm1, Wm2, bm2, o2);
        out[(size_t)(b0 + t) * 2 + 0] = o2[0];
        out[(size_t)(b0 + t) * 2 + 1] = o2[1];
    }
}

// ---------------- launcher ----------------
extern "C" void kernel_launch(void* const* d_in, const int* in_sizes, int n_in,
                              void* d_out, int out_size, void* d_ws, size_t ws_size,
                              hipStream_t stream) {
    if (n_in < 18) return;
    const float* x    = (const float*)d_in[0];
    const float* inp0 = (const float*)d_in[1];
    const float* loc0 = (const float*)d_in[2];
    const float* inp1 = (const float*)d_in[3];
    const float* loc1 = (const float*)d_in[4];
    const float* inp2 = (const float*)d_in[5];
    const float* loc2 = (const float*)d_in[6];
    const float* inp3 = (const float*)d_in[7];
    const float* Wi1  = (const float*)d_in[8];
    const float* bi1  = (const float*)d_in[9];
    const float* Wi2  = (const float*)d_in[10];
    const float* bi2  = (const float*)d_in[11];
    const float* Wi3  = (const float*)d_in[12];
    const float* bi3  = (const float*)d_in[13];
    const float* Wm1  = (const float*)d_in[14];
    const float* bm1  = (const float*)d_in[15];
    const float* Wm2  = (const float*)d_in[16];
    const float* bm2  = (const float*)d_in[17];
    float* out = (float*)d_out;

    if (ws_size >= WS_NEED && d_ws != nullptr) {
        unsigned short* W1t = (unsigned short*)((char*)d_ws + W1T_OFF);
        unsigned short* W2t = (unsigned short*)((char*)d_ws + W2T_OFF);
        float*          yws = (float*)((char*)d_ws + YWS_OFF);

        prep_weights_kernel<<<2112, 256, 0, stream>>>(Wi1, Wi2, W1t, W2t);
        img_gemm_kernel<<<512, 256, 0, stream>>>(x, inp0, loc0, W1t, W2t, bi1, bi2, Wi3, bi3, yws);
        tail_kernel<<<BATCH / 256, 256, 0, stream>>>(yws, inp1, loc1, inp2, loc2, inp3,
                                                     Wm1, bm1, Wm2, bm2, out);
    } else {
        fused_all_kernel<<<BATCH / 64, 256, 0, stream>>>(
            x, inp0, loc0, Wi1, bi1, Wi2, bi2, Wi3, bi3,
            inp1, loc1, inp2, loc2, inp3, Wm1, bm1, Wm2, bm2, out);
    }
}